// Round 3
// baseline (295.599 us; speedup 1.0000x reference)
//
#include <hip/hip_runtime.h>
#include <math.h>

// Chained bilinear lookup: out = bilinear(grid0, bilinear(grid1, x)),
// sigmoid per corner sample (both stages).
//
// Shapes: x (N,2) f32; grid1 (U1,U1,2) f32, U1=2080; grid0 (U0,U0,3) f32,
// U0=520; out (N,3) f32.
//
// PRECISION CONTRACT (R0-R11, passing at absmax 3.9e-3 / thr 1.96e-2):
//  - Ref is a faithful per-op float32 numpy pipeline; stage-1 output is
//    multiplied by 520 in stage 2 (errors amplified ~520x).
//  - su = x*U must be a SINGLE f32 rounded mul (inline-asm v_mul_f32 —
//    default ffp-contract otherwise fuses su-floor into fma => 0.04).
//  - Sigmoid: e = expf(-t) in f32 (1 ulp, matches np.exp-f32), then
//    1/(1+e) in f64 rounded once to f32.
//  - f32 blends as written (R5/R8-validated).
//
// PERF HISTORY:
//  R5: 2 lines/pt stage-1, FETCH 600MB, query 179us.
//  R8: corner-packed stage-1 (32B cell, 1 line/pt): query 123us (BEST
//      query shape); LDS-tiled pack 137us.
//  R9: 2pt/thread -> serialized chains, 150us. FAIL.
//  R10: SoA stage-2 -> 157us. FAIL.
//  R11: f64-exp -> f32-expf+f64-div in all sigmoids. Total ~257us;
//      query 124us, pre-pass still ~128us => sigmoid was NOT the pack
//      bottleneck. Pack runs at ~1.4 TB/s vs 173MB/~35us streaming
//      roofline -> structure-bound (LDS tile, barrier, halo tail).
//  R12: barrier-free fused pack (1 thread = 1 cell, direct corner loads,
//      redundant sigmoids, nontemporal stores). INFRA FAIL (no verdict).
//  R13: resubmit. COMPILE FAIL: __builtin_nontemporal_* rejects
//      HIP_vector_type float4* — must use clang ext_vector_type.
//  R14 (this): same kernel, all nontemporal accesses via f32x4
//      (ext_vector_type). Bit-identical math. Predict pack ~35-55us,
//      query unchanged ~124us, total ~190us.

typedef float f32x2 __attribute__((ext_vector_type(2)));
typedef float f32x4 __attribute__((ext_vector_type(4)));

__device__ __forceinline__ float mul_rn_nocontract(float a, float b) {
    float r;
    asm("v_mul_f32 %0, %1, %2" : "=v"(r) : "v"(a), "v"(b));
    return r;
}

// ~1-ulp sigmoid matching numpy's f32 chain: e rounded to f32 (like
// np.exp on float32), then a single correctly-rounded divide (f64 math
// is immune to any rcp/fast lowering of f32 division).
__device__ __forceinline__ float sigmoid_ref(float t) {
    float e = expf(-t);                      // ocml expf, ~1 ulp f32
    return (float)(1.0 / (1.0 + (double)e)); // exact add+div, one rounding
}

// ---- Phase A1: fused corner-pack of grid1 (barrier-free) ----
// One thread per cell (u,v):
//   pk cell = [s(t00).xy s(t01).xy | s(t10).xy s(t11).xy]
// Grid: x = ceil(U1/256) blocks over v, y = U1 rows (no int div, no LDS,
// no __syncthreads). Corner values recomputed redundantly (4x) — VALU
// cost ~15us across the chip, hidden under the 138MB write stream.
__global__ void __launch_bounds__(256) pack_fused_kernel(
    const float* __restrict__ g1, float* __restrict__ pk, int U1)
{
    int v = blockIdx.x * 256 + threadIdx.x;
    int u = blockIdx.y;
    if (v >= U1) return;
    int v1 = v + 1; if (v1 >= U1) v1 = 0;
    int u1 = u + 1; if (u1 >= U1) u1 = 0;

    const f32x2* g = reinterpret_cast<const f32x2*>(g1);
    size_t ru0 = (size_t)u  * U1;
    size_t ru1 = (size_t)u1 * U1;
    f32x2 t00 = g[ru0 + v];
    f32x2 t01 = g[ru0 + v1];
    f32x2 t10 = g[ru1 + v];
    f32x2 t11 = g[ru1 + v1];

    f32x4 lo, hi;
    lo.x = sigmoid_ref(t00.x); lo.y = sigmoid_ref(t00.y);
    lo.z = sigmoid_ref(t01.x); lo.w = sigmoid_ref(t01.y);
    hi.x = sigmoid_ref(t10.x); hi.y = sigmoid_ref(t10.y);
    hi.z = sigmoid_ref(t11.x); hi.w = sigmoid_ref(t11.y);

    f32x4* o = reinterpret_cast<f32x4*>(pk + (ru0 + v) * 8);
    __builtin_nontemporal_store(lo, o);
    __builtin_nontemporal_store(hi, o + 1);
}

// ---- Phase A2: elementwise sigmoid of a table (float4-vectorized) ----
__global__ void __launch_bounds__(256) sigmoid_table_kernel(
    const float4* __restrict__ in, float4* __restrict__ out, int n4)
{
    int i = blockIdx.x * blockDim.x + threadIdx.x;
    if (i >= n4) return;
    float4 v = in[i];
    float4 r;
    r.x = sigmoid_ref(v.x);
    r.y = sigmoid_ref(v.y);
    r.z = sigmoid_ref(v.z);
    r.w = sigmoid_ref(v.w);
    out[i] = r;
}

// ---- Phase B: R8's query (1 pt/thread, packed stage-1, AoS stage-2) ----
__global__ void __launch_bounds__(256) query_packed_kernel(
    const float* __restrict__ x,
    const float* __restrict__ pk,   // packed corners, U1*U1*8 floats
    const float* __restrict__ s0,   // sigmoid(grid0), (U0,U0,3), L2-resident
    float* __restrict__ out,        // (N,3)
    int N, int U1, int U0)
{
    int i = blockIdx.x * blockDim.x + threadIdx.x;
    if (i >= N) return;

    f32x2 uv = __builtin_nontemporal_load(
        reinterpret_cast<const f32x2*>(x) + i);

    // stage-1 coords: single rounded f32 mul (contract-proof)
    float fU1 = (float)U1;
    float su = mul_rn_nocontract(uv.x, fU1);
    float sv = mul_rn_nocontract(uv.y, fU1);
    float u0f = floorf(su), v0f = floorf(sv);
    float fu = su - u0f;              // exact
    float fv = sv - v0f;
    int u0 = (int)u0f % U1; if (u0 < 0) u0 += U1;
    int v0 = (int)v0f % U1; if (v0 < 0) v0 += U1;

    // ONE 64B line: 32B-aligned packed cell; nontemporal (measured zero
    // captured line-reuse -> keep the 138MB stream out of L2, protect s0)
    const f32x4* cell = reinterpret_cast<const f32x4*>(pk)
                      + (size_t)(u0 * U1 + v0) * 2;
    f32x4 lo = __builtin_nontemporal_load(cell);     // t00.xy t01.xy
    f32x4 hi = __builtin_nontemporal_load(cell + 1); // t10.xy t11.xy

    float omfu = 1.0f - fu, omfv = 1.0f - fv;
    float kx = (lo.x * omfu + hi.x * fu) * omfv
             + (lo.z * omfu + hi.z * fu) * fv;
    float ky = (lo.y * omfu + hi.y * fu) * omfv
             + (lo.w * omfu + hi.w * fu) * fv;

    // stage 2 (R5/R8-validated form, L2-resident 3.2MB AoS table)
    float fU0 = (float)U0;
    float su2 = mul_rn_nocontract(kx, fU0);
    float sv2 = mul_rn_nocontract(ky, fU0);
    float u0f2 = floorf(su2), v0f2 = floorf(sv2);
    float fu2 = su2 - u0f2, fv2 = sv2 - v0f2;
    int p0 = (int)u0f2 % U0; if (p0 < 0) p0 += U0;
    int q0 = (int)v0f2 % U0; if (q0 < 0) q0 += U0;
    int p1 = p0 + 1; if (p1 >= U0) p1 = 0;
    int q1 = q0 + 1; if (q1 >= U0) q1 = 0;
    int b00 = (p0 * U0 + q0) * 3, b10 = (p1 * U0 + q0) * 3;
    int b01 = (p0 * U0 + q1) * 3, b11 = (p1 * U0 + q1) * 3;
    float omfu2 = 1.0f - fu2, omfv2 = 1.0f - fv2;
    float r0 = (s0[b00+0] * omfu2 + s0[b10+0] * fu2) * omfv2
             + (s0[b01+0] * omfu2 + s0[b11+0] * fu2) * fv2;
    float r1 = (s0[b00+1] * omfu2 + s0[b10+1] * fu2) * omfv2
             + (s0[b01+1] * omfu2 + s0[b11+1] * fu2) * fv2;
    float r2 = (s0[b00+2] * omfu2 + s0[b10+2] * fu2) * omfv2
             + (s0[b01+2] * omfu2 + s0[b11+2] * fu2) * fv2;
    out[3*i+0] = r0; out[3*i+1] = r1; out[3*i+2] = r2;
}

// ---- Middle variant: R5's known-good unpadded query kernel ----
__global__ void __launch_bounds__(256) query_kernel_unpadded(
    const float* __restrict__ x,
    const float* __restrict__ s1,
    const float* __restrict__ s0,
    float* __restrict__ out,
    int N, int U1, int U0)
{
    int i = blockIdx.x * blockDim.x + threadIdx.x;
    if (i >= N) return;
    float2 uv = reinterpret_cast<const float2*>(x)[i];
    float fU1 = (float)U1;
    float su = mul_rn_nocontract(uv.x, fU1);
    float sv = mul_rn_nocontract(uv.y, fU1);
    float u0f = floorf(su), v0f = floorf(sv);
    float fu = su - u0f, fv = sv - v0f;
    int u0 = (int)u0f % U1; if (u0 < 0) u0 += U1;
    int v0 = (int)v0f % U1; if (v0 < 0) v0 += U1;
    int u1 = u0 + 1; if (u1 >= U1) u1 = 0;
    int v1 = v0 + 1; if (v1 >= U1) v1 = 0;
    const float2* s1v = reinterpret_cast<const float2*>(s1);
    float2 t00 = s1v[u0 * U1 + v0];
    float2 t10 = s1v[u1 * U1 + v0];
    float2 t01 = s1v[u0 * U1 + v1];
    float2 t11 = s1v[u1 * U1 + v1];
    float omfu = 1.0f - fu, omfv = 1.0f - fv;
    float kx = (t00.x * omfu + t10.x * fu) * omfv + (t01.x * omfu + t11.x * fu) * fv;
    float ky = (t00.y * omfu + t10.y * fu) * omfv + (t01.y * omfu + t11.y * fu) * fv;
    float fU0 = (float)U0;
    float su2 = mul_rn_nocontract(kx, fU0);
    float sv2 = mul_rn_nocontract(ky, fU0);
    float u0f2 = floorf(su2), v0f2 = floorf(sv2);
    float fu2 = su2 - u0f2, fv2 = sv2 - v0f2;
    int p0 = (int)u0f2 % U0; if (p0 < 0) p0 += U0;
    int q0 = (int)v0f2 % U0; if (q0 < 0) q0 += U0;
    int p1 = p0 + 1; if (p1 >= U0) p1 = 0;
    int q1 = q0 + 1; if (q1 >= U0) q1 = 0;
    int b00 = (p0 * U0 + q0) * 3, b10 = (p1 * U0 + q0) * 3;
    int b01 = (p0 * U0 + q1) * 3, b11 = (p1 * U0 + q1) * 3;
    float omfu2 = 1.0f - fu2, omfv2 = 1.0f - fv2;
    float r0 = (s0[b00+0] * omfu2 + s0[b10+0] * fu2) * omfv2
             + (s0[b01+0] * omfu2 + s0[b11+0] * fu2) * fv2;
    float r1 = (s0[b00+1] * omfu2 + s0[b10+1] * fu2) * omfv2
             + (s0[b01+1] * omfu2 + s0[b11+1] * fu2) * fv2;
    float r2 = (s0[b00+2] * omfu2 + s0[b10+2] * fu2) * omfv2
             + (s0[b01+2] * omfu2 + s0[b11+2] * fu2) * fv2;
    out[3*i+0] = r0; out[3*i+1] = r1; out[3*i+2] = r2;
}

// ---- Full fallback: all sigmoids in-kernel (ws too small) ----
__global__ void __launch_bounds__(256) query_kernel_fallback(
    const float* __restrict__ x,
    const float* __restrict__ g1,
    const float* __restrict__ g0,
    float* __restrict__ out,
    int N, int U1, int U0)
{
    int i = blockIdx.x * blockDim.x + threadIdx.x;
    if (i >= N) return;
    float2 uv = reinterpret_cast<const float2*>(x)[i];
    float fU1 = (float)U1;
    float su = mul_rn_nocontract(uv.x, fU1);
    float sv = mul_rn_nocontract(uv.y, fU1);
    float u0f = floorf(su), v0f = floorf(sv);
    float fu = su - u0f, fv = sv - v0f;
    int u0 = (int)u0f % U1; if (u0 < 0) u0 += U1;
    int v0 = (int)v0f % U1; if (v0 < 0) v0 += U1;
    int u1 = u0 + 1; if (u1 >= U1) u1 = 0;
    int v1 = v0 + 1; if (v1 >= U1) v1 = 0;
    const float2* g1v = reinterpret_cast<const float2*>(g1);
    float2 t00 = g1v[u0 * U1 + v0];
    float2 t10 = g1v[u1 * U1 + v0];
    float2 t01 = g1v[u0 * U1 + v1];
    float2 t11 = g1v[u1 * U1 + v1];
    float a00x = sigmoid_ref(t00.x), a00y = sigmoid_ref(t00.y);
    float a10x = sigmoid_ref(t10.x), a10y = sigmoid_ref(t10.y);
    float a01x = sigmoid_ref(t01.x), a01y = sigmoid_ref(t01.y);
    float a11x = sigmoid_ref(t11.x), a11y = sigmoid_ref(t11.y);
    float omfu = 1.0f - fu, omfv = 1.0f - fv;
    float kx = (a00x * omfu + a10x * fu) * omfv + (a01x * omfu + a11x * fu) * fv;
    float ky = (a00y * omfu + a10y * fu) * omfv + (a01y * omfu + a11y * fu) * fv;
    float fU0 = (float)U0;
    float su2 = mul_rn_nocontract(kx, fU0);
    float sv2 = mul_rn_nocontract(ky, fU0);
    float u0f2 = floorf(su2), v0f2 = floorf(sv2);
    float fu2 = su2 - u0f2, fv2 = sv2 - v0f2;
    int p0 = (int)u0f2 % U0; if (p0 < 0) p0 += U0;
    int q0 = (int)v0f2 % U0; if (q0 < 0) q0 += U0;
    int p1 = p0 + 1; if (p1 >= U0) p1 = 0;
    int q1 = q0 + 1; if (q1 >= U0) q1 = 0;
    int b00 = (p0 * U0 + q0) * 3, b10 = (p1 * U0 + q0) * 3;
    int b01 = (p0 * U0 + q1) * 3, b11 = (p1 * U0 + q1) * 3;
    float omfu2 = 1.0f - fu2, omfv2 = 1.0f - fv2;
    float r0 = (sigmoid_ref(g0[b00+0]) * omfu2 + sigmoid_ref(g0[b10+0]) * fu2) * omfv2
             + (sigmoid_ref(g0[b01+0]) * omfu2 + sigmoid_ref(g0[b11+0]) * fu2) * fv2;
    float r1 = (sigmoid_ref(g0[b00+1]) * omfu2 + sigmoid_ref(g0[b10+1]) * fu2) * omfv2
             + (sigmoid_ref(g0[b01+1]) * omfu2 + sigmoid_ref(g0[b11+1]) * fu2) * fv2;
    float r2 = (sigmoid_ref(g0[b00+2]) * omfu2 + sigmoid_ref(g0[b10+2]) * fu2) * omfv2
             + (sigmoid_ref(g0[b01+2]) * omfu2 + sigmoid_ref(g0[b11+2]) * fu2) * fv2;
    out[3*i+0] = r0; out[3*i+1] = r1; out[3*i+2] = r2;
}

extern "C" void kernel_launch(void* const* d_in, const int* in_sizes, int n_in,
                              void* d_out, int out_size, void* d_ws, size_t ws_size,
                              hipStream_t stream) {
    const float* x  = (const float*)d_in[0];
    const float* g1 = (const float*)d_in[1];
    const float* g0 = (const float*)d_in[2];
    float* out = (float*)d_out;

    int N = in_sizes[0] / 2;
    long long n1 = in_sizes[1];          // U1*U1*2
    long long n0 = in_sizes[2];          // U0*U0*3
    int U1 = (int)(sqrt((double)(n1 / 2)) + 0.5);
    int U0 = (int)(sqrt((double)(n0 / 3)) + 0.5);
    long long ncells1 = (long long)U1 * U1;

    int block = 256;
    size_t need_packed = ((size_t)ncells1 * 8 + (size_t)n0) * sizeof(float);
    size_t need_plain  = ((size_t)n1 + (size_t)n0) * sizeof(float);

    if (ws_size >= need_packed && (n0 % 4) == 0) {
        float* pk = (float*)d_ws;                     // 138.4 MB packed
        float* s0 = pk + ncells1 * 8;                 // 3.2 MB sigmoided g0
        int n0_4 = (int)(n0 / 4);
        dim3 pgrid((U1 + block - 1) / block, U1);
        pack_fused_kernel<<<pgrid, block, 0, stream>>>(g1, pk, U1);
        sigmoid_table_kernel<<<(n0_4 + block - 1) / block, block, 0, stream>>>(
            (const float4*)g0, (float4*)s0, n0_4);
        query_packed_kernel<<<(N + block - 1) / block, block, 0, stream>>>(
            x, pk, s0, out, N, U1, U0);
    } else if (ws_size >= need_plain && (n1 % 4) == 0 && (n0 % 4) == 0) {
        float* s1 = (float*)d_ws;
        float* s0 = s1 + n1;
        int n1_4 = (int)(n1 / 4), n0_4 = (int)(n0 / 4);
        sigmoid_table_kernel<<<(n1_4 + block - 1) / block, block, 0, stream>>>(
            (const float4*)g1, (float4*)s1, n1_4);
        sigmoid_table_kernel<<<(n0_4 + block - 1) / block, block, 0, stream>>>(
            (const float4*)g0, (float4*)s0, n0_4);
        query_kernel_unpadded<<<(N + block - 1) / block, block, 0, stream>>>(
            x, s1, s0, out, N, U1, U0);
    } else {
        query_kernel_fallback<<<(N + block - 1) / block, block, 0, stream>>>(
            x, g1, g0, out, N, U1, U0);
    }
}

// Round 4
// 260.354 us; speedup vs baseline: 1.1354x; 1.1354x over previous
//
#include <hip/hip_runtime.h>
#include <math.h>

// Chained bilinear lookup: out = bilinear(grid0, bilinear(grid1, x)),
// sigmoid per corner sample (both stages).
//
// Shapes: x (N,2) f32; grid1 (U1,U1,2) f32, U1=2080; grid0 (U0,U0,3) f32,
// U0=520; out (N,3) f32.
//
// PRECISION CONTRACT (R0-R14, passing at absmax 3.9e-3 / thr 1.96e-2):
//  - Ref is a faithful per-op float32 numpy pipeline; stage-1 output is
//    multiplied by 520 in stage 2 (errors amplified ~520x).
//  - su = x*U must be a SINGLE f32 rounded mul (inline-asm v_mul_f32 —
//    default ffp-contract otherwise fuses su-floor into fma => 0.04).
//  - Sigmoid: e = expf(-t) in f32 (1 ulp, matches np.exp-f32), then
//    1/(1+e) in f64 rounded once to f32.
//  - f32 blends as written (R5/R8-validated).
//
// PERF HISTORY:
//  R5: 2 lines/pt stage-1, FETCH 600MB, query 179us.
//  R8: corner-packed stage-1 (32B cell, 1 line/pt): query 123us (BEST
//      query shape); LDS-tiled pack 137us.
//  R9: 2pt/thread -> serialized chains, 150us. FAIL.
//  R10: SoA stage-2 -> 157us. FAIL.
//  R11: f64-exp -> f32-expf+f64-div sigmoids. Total 257.1us; query
//      124.7us / FETCH 312MB / 2.99TB/s; pre-pass remainder 132.4us.
//  R12/R13: fused pack + nt everywhere. infra fail, then compile fail
//      (__builtin_nontemporal_* needs ext_vector_type, not HIP float4).
//  R14: MEASURED: nt pk loads in query = -41% (124.7->175.4us, FETCH
//      ~same, BW 2.99->2.04TB/s) — nt bypasses L1/evict-first L2, kills
//      short-window line reuse in a latency-bound kernel. REVERT.
//      Fused pack (nt stores): remainder 132.4->120.2us => fused beats
//      tiled by ~12us. KEEP structure.
//  R15 (this): query = R11 exact (plain cell loads, nt only on x);
//      fused pack with PLAIN stores (let pk lines retire L2->L3; 256MB
//      L3 holds all 138MB of pk => query's random cell reads can hit
//      L3). Predict query ~124us, total ~235-245us.

typedef float f32x2 __attribute__((ext_vector_type(2)));
typedef float f32x4 __attribute__((ext_vector_type(4)));

__device__ __forceinline__ float mul_rn_nocontract(float a, float b) {
    float r;
    asm("v_mul_f32 %0, %1, %2" : "=v"(r) : "v"(a), "v"(b));
    return r;
}

// ~1-ulp sigmoid matching numpy's f32 chain: e rounded to f32 (like
// np.exp on float32), then a single correctly-rounded divide (f64 math
// is immune to any rcp/fast lowering of f32 division).
__device__ __forceinline__ float sigmoid_ref(float t) {
    float e = expf(-t);                      // ocml expf, ~1 ulp f32
    return (float)(1.0 / (1.0 + (double)e)); // exact add+div, one rounding
}

// ---- Phase A1: fused corner-pack of grid1 (barrier-free) ----
// One thread per cell (u,v):
//   pk cell = [s(t00).xy s(t01).xy | s(t10).xy s(t11).xy]
// Grid: x = ceil(U1/256) blocks over v, y = U1 rows (no int div, no LDS,
// no __syncthreads). Corner values recomputed redundantly (4x) — VALU
// cost ~15us across the chip, hidden under the 138MB write stream.
// Stores are PLAIN (not nt): dirty pk lines retire L2->L3 and stay
// L3-resident for the downstream query's random reads.
__global__ void __launch_bounds__(256) pack_fused_kernel(
    const float* __restrict__ g1, float* __restrict__ pk, int U1)
{
    int v = blockIdx.x * 256 + threadIdx.x;
    int u = blockIdx.y;
    if (v >= U1) return;
    int v1 = v + 1; if (v1 >= U1) v1 = 0;
    int u1 = u + 1; if (u1 >= U1) u1 = 0;

    const f32x2* g = reinterpret_cast<const f32x2*>(g1);
    size_t ru0 = (size_t)u  * U1;
    size_t ru1 = (size_t)u1 * U1;
    f32x2 t00 = g[ru0 + v];
    f32x2 t01 = g[ru0 + v1];
    f32x2 t10 = g[ru1 + v];
    f32x2 t11 = g[ru1 + v1];

    f32x4 lo, hi;
    lo.x = sigmoid_ref(t00.x); lo.y = sigmoid_ref(t00.y);
    lo.z = sigmoid_ref(t01.x); lo.w = sigmoid_ref(t01.y);
    hi.x = sigmoid_ref(t10.x); hi.y = sigmoid_ref(t10.y);
    hi.z = sigmoid_ref(t11.x); hi.w = sigmoid_ref(t11.y);

    f32x4* o = reinterpret_cast<f32x4*>(pk + (ru0 + v) * 8);
    o[0] = lo;
    o[1] = hi;
}

// ---- Phase A2: elementwise sigmoid of a table (float4-vectorized) ----
__global__ void __launch_bounds__(256) sigmoid_table_kernel(
    const float4* __restrict__ in, float4* __restrict__ out, int n4)
{
    int i = blockIdx.x * blockDim.x + threadIdx.x;
    if (i >= n4) return;
    float4 v = in[i];
    float4 r;
    r.x = sigmoid_ref(v.x);
    r.y = sigmoid_ref(v.y);
    r.z = sigmoid_ref(v.z);
    r.w = sigmoid_ref(v.w);
    out[i] = r;
}

// ---- Phase B: R8/R11 query (1 pt/thread, packed stage-1, AoS stage-2) ----
__global__ void __launch_bounds__(256) query_packed_kernel(
    const float* __restrict__ x,
    const float* __restrict__ pk,   // packed corners, U1*U1*8 floats
    const float* __restrict__ s0,   // sigmoid(grid0), (U0,U0,3), L2-resident
    float* __restrict__ out,        // (N,3)
    int N, int U1, int U0)
{
    int i = blockIdx.x * blockDim.x + threadIdx.x;
    if (i >= N) return;

    f32x2 uv = __builtin_nontemporal_load(
        reinterpret_cast<const f32x2*>(x) + i);

    // stage-1 coords: single rounded f32 mul (contract-proof)
    float fU1 = (float)U1;
    float su = mul_rn_nocontract(uv.x, fU1);
    float sv = mul_rn_nocontract(uv.y, fU1);
    float u0f = floorf(su), v0f = floorf(sv);
    float fu = su - u0f;              // exact
    float fv = sv - v0f;
    int u0 = (int)u0f % U1; if (u0 < 0) u0 += U1;
    int v0 = (int)v0f % U1; if (v0 < 0) v0 += U1;

    // ONE 64B line: 32B-aligned packed cell. PLAIN loads (R14: nt here
    // cost +41% — bypassing L1/evict-first L2 kills line reuse in this
    // latency-bound kernel).
    const float4* cell = reinterpret_cast<const float4*>(pk)
                       + (size_t)(u0 * U1 + v0) * 2;
    float4 lo = cell[0];   // t00.xy t01.xy
    float4 hi = cell[1];   // t10.xy t11.xy

    float omfu = 1.0f - fu, omfv = 1.0f - fv;
    float kx = (lo.x * omfu + hi.x * fu) * omfv
             + (lo.z * omfu + hi.z * fu) * fv;
    float ky = (lo.y * omfu + hi.y * fu) * omfv
             + (lo.w * omfu + hi.w * fu) * fv;

    // stage 2 (R5/R8-validated form, L2-resident 3.2MB AoS table)
    float fU0 = (float)U0;
    float su2 = mul_rn_nocontract(kx, fU0);
    float sv2 = mul_rn_nocontract(ky, fU0);
    float u0f2 = floorf(su2), v0f2 = floorf(sv2);
    float fu2 = su2 - u0f2, fv2 = sv2 - v0f2;
    int p0 = (int)u0f2 % U0; if (p0 < 0) p0 += U0;
    int q0 = (int)v0f2 % U0; if (q0 < 0) q0 += U0;
    int p1 = p0 + 1; if (p1 >= U0) p1 = 0;
    int q1 = q0 + 1; if (q1 >= U0) q1 = 0;
    int b00 = (p0 * U0 + q0) * 3, b10 = (p1 * U0 + q0) * 3;
    int b01 = (p0 * U0 + q1) * 3, b11 = (p1 * U0 + q1) * 3;
    float omfu2 = 1.0f - fu2, omfv2 = 1.0f - fv2;
    float r0 = (s0[b00+0] * omfu2 + s0[b10+0] * fu2) * omfv2
             + (s0[b01+0] * omfu2 + s0[b11+0] * fu2) * fv2;
    float r1 = (s0[b00+1] * omfu2 + s0[b10+1] * fu2) * omfv2
             + (s0[b01+1] * omfu2 + s0[b11+1] * fu2) * fv2;
    float r2 = (s0[b00+2] * omfu2 + s0[b10+2] * fu2) * omfv2
             + (s0[b01+2] * omfu2 + s0[b11+2] * fu2) * fv2;
    out[3*i+0] = r0; out[3*i+1] = r1; out[3*i+2] = r2;
}

// ---- Middle variant: R5's known-good unpadded query kernel ----
__global__ void __launch_bounds__(256) query_kernel_unpadded(
    const float* __restrict__ x,
    const float* __restrict__ s1,
    const float* __restrict__ s0,
    float* __restrict__ out,
    int N, int U1, int U0)
{
    int i = blockIdx.x * blockDim.x + threadIdx.x;
    if (i >= N) return;
    float2 uv = reinterpret_cast<const float2*>(x)[i];
    float fU1 = (float)U1;
    float su = mul_rn_nocontract(uv.x, fU1);
    float sv = mul_rn_nocontract(uv.y, fU1);
    float u0f = floorf(su), v0f = floorf(sv);
    float fu = su - u0f, fv = sv - v0f;
    int u0 = (int)u0f % U1; if (u0 < 0) u0 += U1;
    int v0 = (int)v0f % U1; if (v0 < 0) v0 += U1;
    int u1 = u0 + 1; if (u1 >= U1) u1 = 0;
    int v1 = v0 + 1; if (v1 >= U1) v1 = 0;
    const float2* s1v = reinterpret_cast<const float2*>(s1);
    float2 t00 = s1v[u0 * U1 + v0];
    float2 t10 = s1v[u1 * U1 + v0];
    float2 t01 = s1v[u0 * U1 + v1];
    float2 t11 = s1v[u1 * U1 + v1];
    float omfu = 1.0f - fu, omfv = 1.0f - fv;
    float kx = (t00.x * omfu + t10.x * fu) * omfv + (t01.x * omfu + t11.x * fu) * fv;
    float ky = (t00.y * omfu + t10.y * fu) * omfv + (t01.y * omfu + t11.y * fu) * fv;
    float fU0 = (float)U0;
    float su2 = mul_rn_nocontract(kx, fU0);
    float sv2 = mul_rn_nocontract(ky, fU0);
    float u0f2 = floorf(su2), v0f2 = floorf(sv2);
    float fu2 = su2 - u0f2, fv2 = sv2 - v0f2;
    int p0 = (int)u0f2 % U0; if (p0 < 0) p0 += U0;
    int q0 = (int)v0f2 % U0; if (q0 < 0) q0 += U0;
    int p1 = p0 + 1; if (p1 >= U0) p1 = 0;
    int q1 = q0 + 1; if (q1 >= U0) q1 = 0;
    int b00 = (p0 * U0 + q0) * 3, b10 = (p1 * U0 + q0) * 3;
    int b01 = (p0 * U0 + q1) * 3, b11 = (p1 * U0 + q1) * 3;
    float omfu2 = 1.0f - fu2, omfv2 = 1.0f - fv2;
    float r0 = (s0[b00+0] * omfu2 + s0[b10+0] * fu2) * omfv2
             + (s0[b01+0] * omfu2 + s0[b11+0] * fu2) * fv2;
    float r1 = (s0[b00+1] * omfu2 + s0[b10+1] * fu2) * omfv2
             + (s0[b01+1] * omfu2 + s0[b11+1] * fu2) * fv2;
    float r2 = (s0[b00+2] * omfu2 + s0[b10+2] * fu2) * omfv2
             + (s0[b01+2] * omfu2 + s0[b11+2] * fu2) * fv2;
    out[3*i+0] = r0; out[3*i+1] = r1; out[3*i+2] = r2;
}

// ---- Full fallback: all sigmoids in-kernel (ws too small) ----
__global__ void __launch_bounds__(256) query_kernel_fallback(
    const float* __restrict__ x,
    const float* __restrict__ g1,
    const float* __restrict__ g0,
    float* __restrict__ out,
    int N, int U1, int U0)
{
    int i = blockIdx.x * blockDim.x + threadIdx.x;
    if (i >= N) return;
    float2 uv = reinterpret_cast<const float2*>(x)[i];
    float fU1 = (float)U1;
    float su = mul_rn_nocontract(uv.x, fU1);
    float sv = mul_rn_nocontract(uv.y, fU1);
    float u0f = floorf(su), v0f = floorf(sv);
    float fu = su - u0f, fv = sv - v0f;
    int u0 = (int)u0f % U1; if (u0 < 0) u0 += U1;
    int v0 = (int)v0f % U1; if (v0 < 0) v0 += U1;
    int u1 = u0 + 1; if (u1 >= U1) u1 = 0;
    int v1 = v0 + 1; if (v1 >= U1) v1 = 0;
    const float2* g1v = reinterpret_cast<const float2*>(g1);
    float2 t00 = g1v[u0 * U1 + v0];
    float2 t10 = g1v[u1 * U1 + v0];
    float2 t01 = g1v[u0 * U1 + v1];
    float2 t11 = g1v[u1 * U1 + v1];
    float a00x = sigmoid_ref(t00.x), a00y = sigmoid_ref(t00.y);
    float a10x = sigmoid_ref(t10.x), a10y = sigmoid_ref(t10.y);
    float a01x = sigmoid_ref(t01.x), a01y = sigmoid_ref(t01.y);
    float a11x = sigmoid_ref(t11.x), a11y = sigmoid_ref(t11.y);
    float omfu = 1.0f - fu, omfv = 1.0f - fv;
    float kx = (a00x * omfu + a10x * fu) * omfv + (a01x * omfu + a11x * fu) * fv;
    float ky = (a00y * omfu + a10y * fu) * omfv + (a01y * omfu + a11y * fu) * fv;
    float fU0 = (float)U0;
    float su2 = mul_rn_nocontract(kx, fU0);
    float sv2 = mul_rn_nocontract(ky, fU0);
    float u0f2 = floorf(su2), v0f2 = floorf(sv2);
    float fu2 = su2 - u0f2, fv2 = sv2 - v0f2;
    int p0 = (int)u0f2 % U0; if (p0 < 0) p0 += U0;
    int q0 = (int)v0f2 % U0; if (q0 < 0) q0 += U0;
    int p1 = p0 + 1; if (p1 >= U0) p1 = 0;
    int q1 = q0 + 1; if (q1 >= U0) q1 = 0;
    int b00 = (p0 * U0 + q0) * 3, b10 = (p1 * U0 + q0) * 3;
    int b01 = (p0 * U0 + q1) * 3, b11 = (p1 * U0 + q1) * 3;
    float omfu2 = 1.0f - fu2, omfv2 = 1.0f - fv2;
    float r0 = (sigmoid_ref(g0[b00+0]) * omfu2 + sigmoid_ref(g0[b10+0]) * fu2) * omfv2
             + (sigmoid_ref(g0[b01+0]) * omfu2 + sigmoid_ref(g0[b11+0]) * fu2) * fv2;
    float r1 = (sigmoid_ref(g0[b00+1]) * omfu2 + sigmoid_ref(g0[b10+1]) * fu2) * omfv2
             + (sigmoid_ref(g0[b01+1]) * omfu2 + sigmoid_ref(g0[b11+1]) * fu2) * fv2;
    float r2 = (sigmoid_ref(g0[b00+2]) * omfu2 + sigmoid_ref(g0[b10+2]) * fu2) * omfv2
             + (sigmoid_ref(g0[b01+2]) * omfu2 + sigmoid_ref(g0[b11+2]) * fu2) * fv2;
    out[3*i+0] = r0; out[3*i+1] = r1; out[3*i+2] = r2;
}

extern "C" void kernel_launch(void* const* d_in, const int* in_sizes, int n_in,
                              void* d_out, int out_size, void* d_ws, size_t ws_size,
                              hipStream_t stream) {
    const float* x  = (const float*)d_in[0];
    const float* g1 = (const float*)d_in[1];
    const float* g0 = (const float*)d_in[2];
    float* out = (float*)d_out;

    int N = in_sizes[0] / 2;
    long long n1 = in_sizes[1];          // U1*U1*2
    long long n0 = in_sizes[2];          // U0*U0*3
    int U1 = (int)(sqrt((double)(n1 / 2)) + 0.5);
    int U0 = (int)(sqrt((double)(n0 / 3)) + 0.5);
    long long ncells1 = (long long)U1 * U1;

    int block = 256;
    size_t need_packed = ((size_t)ncells1 * 8 + (size_t)n0) * sizeof(float);
    size_t need_plain  = ((size_t)n1 + (size_t)n0) * sizeof(float);

    if (ws_size >= need_packed && (n0 % 4) == 0) {
        float* pk = (float*)d_ws;                     // 138.4 MB packed
        float* s0 = pk + ncells1 * 8;                 // 3.2 MB sigmoided g0
        int n0_4 = (int)(n0 / 4);
        dim3 pgrid((U1 + block - 1) / block, U1);
        pack_fused_kernel<<<pgrid, block, 0, stream>>>(g1, pk, U1);
        sigmoid_table_kernel<<<(n0_4 + block - 1) / block, block, 0, stream>>>(
            (const float4*)g0, (float4*)s0, n0_4);
        query_packed_kernel<<<(N + block - 1) / block, block, 0, stream>>>(
            x, pk, s0, out, N, U1, U0);
    } else if (ws_size >= need_plain && (n1 % 4) == 0 && (n0 % 4) == 0) {
        float* s1 = (float*)d_ws;
        float* s0 = s1 + n1;
        int n1_4 = (int)(n1 / 4), n0_4 = (int)(n0 / 4);
        sigmoid_table_kernel<<<(n1_4 + block - 1) / block, block, 0, stream>>>(
            (const float4*)g1, (float4*)s1, n1_4);
        sigmoid_table_kernel<<<(n0_4 + block - 1) / block, block, 0, stream>>>(
            (const float4*)g0, (float4*)s0, n0_4);
        query_kernel_unpadded<<<(N + block - 1) / block, block, 0, stream>>>(
            x, s1, s0, out, N, U1, U0);
    } else {
        query_kernel_fallback<<<(N + block - 1) / block, block, 0, stream>>>(
            x, g1, g0, out, N, U1, U0);
    }
}

// Round 5
// 251.812 us; speedup vs baseline: 1.1739x; 1.0339x over previous
//
#include <hip/hip_runtime.h>
#include <math.h>

// Chained bilinear lookup: out = bilinear(grid0, bilinear(grid1, x)),
// sigmoid per corner sample (both stages).
//
// Shapes: x (N,2) f32; grid1 (U1,U1,2) f32, U1=2080; grid0 (U0,U0,3) f32,
// U0=520; out (N,3) f32.
//
// PRECISION CONTRACT (R0-R15, passing at absmax 3.9e-3 / thr 1.96e-2):
//  - Ref is a faithful per-op float32 numpy pipeline; stage-1 output is
//    multiplied by 520 in stage 2 (errors amplified ~520x).
//  - su = x*U must be a SINGLE f32 rounded mul (inline-asm v_mul_f32 —
//    default ffp-contract otherwise fuses su-floor into fma => 0.04).
//  - Sigmoid: e = expf(-t) in f32 (1 ulp, matches np.exp-f32), then
//    1/(1+e) in f64 rounded once to f32. Moving sigmoid between pack
//    and query is value-identical (same fn, same inputs, same order).
//  - f32 blends as written (R5/R8-validated).
//
// PERF HISTORY:
//  R5:  2 lines/pt stage-1 (s1 direct), FETCH 600MB, query 179us.
//  R8:  corner-packed 32B cell: query 123us; LDS-tiled pack 137us.
//  R9:  2pt/thread -> serialized chains. FAIL. R10: SoA stage-2. FAIL.
//  R11: f32-expf+f64-div sigmoids. Total 257.1; query 124.7 (FETCH
//       312MB, 2.99TB/s), remainder 132.4.
//  R14: nt pk loads in query = -41% (BW 2.99->2.04TB/s): nt bypasses
//       L1/evict-first L2, kills line reuse. REVERT. Fused pack with nt
//       stores: remainder 120.2 (vs tiled 132.4).
//  R15: fused pack plain stores: remainder 136.6. => nt stores worth
//       ~16us in pack; pk L3 residency worth ZERO to query (123.7
//       regardless). Pack pays ~4x/byte premium vs streaming roofline
//       across 3 structures — write-stream dominated, cause unknown.
//  R16 (this): shift bytes from slow pack to measured-3TB/s query:
//       16B ROW-PAIR raw repack rp[u][v]={g1[u][v].xy, g1[u+1][v].xy}
//       (writes 69MB not 138, no sigmoid, nt stores) + query reads
//       entries v0,v0+1 (exp. 80B/pt = 335MB) and computes the 8
//       stage-1 sigmoids in-kernel (hidden under memory latency;
//       VALUBusy 15%->~30%). Predict query 140-150us, pack 20-60us,
//       total 175-215us, absmax unchanged 0.00390625.

typedef float f32x2 __attribute__((ext_vector_type(2)));
typedef float f32x4 __attribute__((ext_vector_type(4)));

__device__ __forceinline__ float mul_rn_nocontract(float a, float b) {
    float r;
    asm("v_mul_f32 %0, %1, %2" : "=v"(r) : "v"(a), "v"(b));
    return r;
}

// ~1-ulp sigmoid matching numpy's f32 chain: e rounded to f32 (like
// np.exp on float32), then a single correctly-rounded divide (f64 math
// is immune to any rcp/fast lowering of f32 division).
__device__ __forceinline__ float sigmoid_ref(float t) {
    float e = expf(-t);                      // ocml expf, ~1 ulp f32
    return (float)(1.0 / (1.0 + (double)e)); // exact add+div, one rounding
}

// ---- Phase A1: raw row-pair repack of grid1 (pure memory stream) ----
// rp[u][v] = {g1[u][v].x, g1[u][v].y, g1[u+1 mod U1][v].x, .y}  (16B)
// No sigmoid, no LDS, no barrier. nt stores (R14: +16us vs plain).
__global__ void __launch_bounds__(256) rowpair_pack_kernel(
    const float* __restrict__ g1, float* __restrict__ rp, int U1)
{
    int v = blockIdx.x * 256 + threadIdx.x;
    int u = blockIdx.y;
    if (v >= U1) return;
    int u1 = u + 1; if (u1 >= U1) u1 = 0;

    const f32x2* g = reinterpret_cast<const f32x2*>(g1);
    f32x2 a = g[(size_t)u  * U1 + v];
    f32x2 b = g[(size_t)u1 * U1 + v];
    f32x4 e;
    e.x = a.x; e.y = a.y; e.z = b.x; e.w = b.y;
    __builtin_nontemporal_store(
        e, reinterpret_cast<f32x4*>(rp) + ((size_t)u * U1 + v));
}

// ---- Phase A2: elementwise sigmoid of a table (float4-vectorized) ----
__global__ void __launch_bounds__(256) sigmoid_table_kernel(
    const float4* __restrict__ in, float4* __restrict__ out, int n4)
{
    int i = blockIdx.x * blockDim.x + threadIdx.x;
    if (i >= n4) return;
    float4 v = in[i];
    float4 r;
    r.x = sigmoid_ref(v.x);
    r.y = sigmoid_ref(v.y);
    r.z = sigmoid_ref(v.z);
    r.w = sigmoid_ref(v.w);
    out[i] = r;
}

// ---- Phase B: row-pair query (1 pt/thread, sigmoid in-kernel) ----
__global__ void __launch_bounds__(256) query_rowpair_kernel(
    const float* __restrict__ x,
    const float* __restrict__ rp,   // row-pair raw corners, U1*U1*4 floats
    const float* __restrict__ s0,   // sigmoid(grid0), (U0,U0,3), L2-resident
    float* __restrict__ out,        // (N,3)
    int N, int U1, int U0)
{
    int i = blockIdx.x * blockDim.x + threadIdx.x;
    if (i >= N) return;

    f32x2 uv = __builtin_nontemporal_load(
        reinterpret_cast<const f32x2*>(x) + i);

    // stage-1 coords: single rounded f32 mul (contract-proof)
    float fU1 = (float)U1;
    float su = mul_rn_nocontract(uv.x, fU1);
    float sv = mul_rn_nocontract(uv.y, fU1);
    float u0f = floorf(su), v0f = floorf(sv);
    float fu = su - u0f;              // exact
    float fv = sv - v0f;
    int u0 = (int)u0f % U1; if (u0 < 0) u0 += U1;
    int v0 = (int)v0f % U1; if (v0 < 0) v0 += U1;
    int v1 = v0 + 1; if (v1 >= U1) v1 = 0;

    // two adjacent 16B entries (32B span, 1 line 75% / 2 lines 25%);
    // PLAIN loads (R14: nt loads cost +41% here)
    const f32x4* rpv = reinterpret_cast<const f32x4*>(rp)
                     + (size_t)u0 * U1;
    f32x4 e0 = rpv[v0];   // t00.xy | t10.xy
    f32x4 e1 = rpv[v1];   // t01.xy | t11.xy

    // stage-1 sigmoids in-kernel (identical fn/order as packed path)
    float a00x = sigmoid_ref(e0.x), a00y = sigmoid_ref(e0.y);
    float a10x = sigmoid_ref(e0.z), a10y = sigmoid_ref(e0.w);
    float a01x = sigmoid_ref(e1.x), a01y = sigmoid_ref(e1.y);
    float a11x = sigmoid_ref(e1.z), a11y = sigmoid_ref(e1.w);

    float omfu = 1.0f - fu, omfv = 1.0f - fv;
    float kx = (a00x * omfu + a10x * fu) * omfv
             + (a01x * omfu + a11x * fu) * fv;
    float ky = (a00y * omfu + a10y * fu) * omfv
             + (a01y * omfu + a11y * fu) * fv;

    // stage 2 (R5/R8-validated form, L2-resident 3.2MB AoS table)
    float fU0 = (float)U0;
    float su2 = mul_rn_nocontract(kx, fU0);
    float sv2 = mul_rn_nocontract(ky, fU0);
    float u0f2 = floorf(su2), v0f2 = floorf(sv2);
    float fu2 = su2 - u0f2, fv2 = sv2 - v0f2;
    int p0 = (int)u0f2 % U0; if (p0 < 0) p0 += U0;
    int q0 = (int)v0f2 % U0; if (q0 < 0) q0 += U0;
    int p1 = p0 + 1; if (p1 >= U0) p1 = 0;
    int q1 = q0 + 1; if (q1 >= U0) q1 = 0;
    int b00 = (p0 * U0 + q0) * 3, b10 = (p1 * U0 + q0) * 3;
    int b01 = (p0 * U0 + q1) * 3, b11 = (p1 * U0 + q1) * 3;
    float omfu2 = 1.0f - fu2, omfv2 = 1.0f - fv2;
    float r0 = (s0[b00+0] * omfu2 + s0[b10+0] * fu2) * omfv2
             + (s0[b01+0] * omfu2 + s0[b11+0] * fu2) * fv2;
    float r1 = (s0[b00+1] * omfu2 + s0[b10+1] * fu2) * omfv2
             + (s0[b01+1] * omfu2 + s0[b11+1] * fu2) * fv2;
    float r2 = (s0[b00+2] * omfu2 + s0[b10+2] * fu2) * omfv2
             + (s0[b01+2] * omfu2 + s0[b11+2] * fu2) * fv2;
    out[3*i+0] = r0; out[3*i+1] = r1; out[3*i+2] = r2;
}

// ---- Middle variant: R5's known-good unpadded query kernel ----
__global__ void __launch_bounds__(256) query_kernel_unpadded(
    const float* __restrict__ x,
    const float* __restrict__ s1,
    const float* __restrict__ s0,
    float* __restrict__ out,
    int N, int U1, int U0)
{
    int i = blockIdx.x * blockDim.x + threadIdx.x;
    if (i >= N) return;
    float2 uv = reinterpret_cast<const float2*>(x)[i];
    float fU1 = (float)U1;
    float su = mul_rn_nocontract(uv.x, fU1);
    float sv = mul_rn_nocontract(uv.y, fU1);
    float u0f = floorf(su), v0f = floorf(sv);
    float fu = su - u0f, fv = sv - v0f;
    int u0 = (int)u0f % U1; if (u0 < 0) u0 += U1;
    int v0 = (int)v0f % U1; if (v0 < 0) v0 += U1;
    int u1 = u0 + 1; if (u1 >= U1) u1 = 0;
    int v1 = v0 + 1; if (v1 >= U1) v1 = 0;
    const float2* s1v = reinterpret_cast<const float2*>(s1);
    float2 t00 = s1v[u0 * U1 + v0];
    float2 t10 = s1v[u1 * U1 + v0];
    float2 t01 = s1v[u0 * U1 + v1];
    float2 t11 = s1v[u1 * U1 + v1];
    float omfu = 1.0f - fu, omfv = 1.0f - fv;
    float kx = (t00.x * omfu + t10.x * fu) * omfv + (t01.x * omfu + t11.x * fu) * fv;
    float ky = (t00.y * omfu + t10.y * fu) * omfv + (t01.y * omfu + t11.y * fu) * fv;
    float fU0 = (float)U0;
    float su2 = mul_rn_nocontract(kx, fU0);
    float sv2 = mul_rn_nocontract(ky, fU0);
    float u0f2 = floorf(su2), v0f2 = floorf(sv2);
    float fu2 = su2 - u0f2, fv2 = sv2 - v0f2;
    int p0 = (int)u0f2 % U0; if (p0 < 0) p0 += U0;
    int q0 = (int)v0f2 % U0; if (q0 < 0) q0 += U0;
    int p1 = p0 + 1; if (p1 >= U0) p1 = 0;
    int q1 = q0 + 1; if (q1 >= U0) q1 = 0;
    int b00 = (p0 * U0 + q0) * 3, b10 = (p1 * U0 + q0) * 3;
    int b01 = (p0 * U0 + q1) * 3, b11 = (p1 * U0 + q1) * 3;
    float omfu2 = 1.0f - fu2, omfv2 = 1.0f - fv2;
    float r0 = (s0[b00+0] * omfu2 + s0[b10+0] * fu2) * omfv2
             + (s0[b01+0] * omfu2 + s0[b11+0] * fu2) * fv2;
    float r1 = (s0[b00+1] * omfu2 + s0[b10+1] * fu2) * omfv2
             + (s0[b01+1] * omfu2 + s0[b11+1] * fu2) * fv2;
    float r2 = (s0[b00+2] * omfu2 + s0[b10+2] * fu2) * omfv2
             + (s0[b01+2] * omfu2 + s0[b11+2] * fu2) * fv2;
    out[3*i+0] = r0; out[3*i+1] = r1; out[3*i+2] = r2;
}

// ---- Full fallback: all sigmoids in-kernel (ws too small) ----
__global__ void __launch_bounds__(256) query_kernel_fallback(
    const float* __restrict__ x,
    const float* __restrict__ g1,
    const float* __restrict__ g0,
    float* __restrict__ out,
    int N, int U1, int U0)
{
    int i = blockIdx.x * blockDim.x + threadIdx.x;
    if (i >= N) return;
    float2 uv = reinterpret_cast<const float2*>(x)[i];
    float fU1 = (float)U1;
    float su = mul_rn_nocontract(uv.x, fU1);
    float sv = mul_rn_nocontract(uv.y, fU1);
    float u0f = floorf(su), v0f = floorf(sv);
    float fu = su - u0f, fv = sv - v0f;
    int u0 = (int)u0f % U1; if (u0 < 0) u0 += U1;
    int v0 = (int)v0f % U1; if (v0 < 0) v0 += U1;
    int u1 = u0 + 1; if (u1 >= U1) u1 = 0;
    int v1 = v0 + 1; if (v1 >= U1) v1 = 0;
    const float2* g1v = reinterpret_cast<const float2*>(g1);
    float2 t00 = g1v[u0 * U1 + v0];
    float2 t10 = g1v[u1 * U1 + v0];
    float2 t01 = g1v[u0 * U1 + v1];
    float2 t11 = g1v[u1 * U1 + v1];
    float a00x = sigmoid_ref(t00.x), a00y = sigmoid_ref(t00.y);
    float a10x = sigmoid_ref(t10.x), a10y = sigmoid_ref(t10.y);
    float a01x = sigmoid_ref(t01.x), a01y = sigmoid_ref(t01.y);
    float a11x = sigmoid_ref(t11.x), a11y = sigmoid_ref(t11.y);
    float omfu = 1.0f - fu, omfv = 1.0f - fv;
    float kx = (a00x * omfu + a10x * fu) * omfv + (a01x * omfu + a11x * fu) * fv;
    float ky = (a00y * omfu + a10y * fu) * omfv + (a01y * omfu + a11y * fu) * fv;
    float fU0 = (float)U0;
    float su2 = mul_rn_nocontract(kx, fU0);
    float sv2 = mul_rn_nocontract(ky, fU0);
    float u0f2 = floorf(su2), v0f2 = floorf(sv2);
    float fu2 = su2 - u0f2, fv2 = sv2 - v0f2;
    int p0 = (int)u0f2 % U0; if (p0 < 0) p0 += U0;
    int q0 = (int)v0f2 % U0; if (q0 < 0) q0 += U0;
    int p1 = p0 + 1; if (p1 >= U0) p1 = 0;
    int q1 = q0 + 1; if (q1 >= U0) q1 = 0;
    int b00 = (p0 * U0 + q0) * 3, b10 = (p1 * U0 + q0) * 3;
    int b01 = (p0 * U0 + q1) * 3, b11 = (p1 * U0 + q1) * 3;
    float omfu2 = 1.0f - fu2, omfv2 = 1.0f - fv2;
    float r0 = (sigmoid_ref(g0[b00+0]) * omfu2 + sigmoid_ref(g0[b10+0]) * fu2) * omfv2
             + (sigmoid_ref(g0[b01+0]) * omfu2 + sigmoid_ref(g0[b11+0]) * fu2) * fv2;
    float r1 = (sigmoid_ref(g0[b00+1]) * omfu2 + sigmoid_ref(g0[b10+1]) * fu2) * omfv2
             + (sigmoid_ref(g0[b01+1]) * omfu2 + sigmoid_ref(g0[b11+1]) * fu2) * fv2;
    float r2 = (sigmoid_ref(g0[b00+2]) * omfu2 + sigmoid_ref(g0[b10+2]) * fu2) * omfv2
             + (sigmoid_ref(g0[b01+2]) * omfu2 + sigmoid_ref(g0[b11+2]) * fu2) * fv2;
    out[3*i+0] = r0; out[3*i+1] = r1; out[3*i+2] = r2;
}

extern "C" void kernel_launch(void* const* d_in, const int* in_sizes, int n_in,
                              void* d_out, int out_size, void* d_ws, size_t ws_size,
                              hipStream_t stream) {
    const float* x  = (const float*)d_in[0];
    const float* g1 = (const float*)d_in[1];
    const float* g0 = (const float*)d_in[2];
    float* out = (float*)d_out;

    int N = in_sizes[0] / 2;
    long long n1 = in_sizes[1];          // U1*U1*2
    long long n0 = in_sizes[2];          // U0*U0*3
    int U1 = (int)(sqrt((double)(n1 / 2)) + 0.5);
    int U0 = (int)(sqrt((double)(n0 / 3)) + 0.5);
    long long ncells1 = (long long)U1 * U1;

    int block = 256;
    size_t need_rowpair = ((size_t)ncells1 * 4 + (size_t)n0) * sizeof(float);
    size_t need_plain   = ((size_t)n1 + (size_t)n0) * sizeof(float);

    if (ws_size >= need_rowpair && (n0 % 4) == 0) {
        float* rp = (float*)d_ws;                     // 69.2 MB row-pair raw
        float* s0 = rp + ncells1 * 4;                 // 3.2 MB sigmoided g0
        int n0_4 = (int)(n0 / 4);
        dim3 pgrid((U1 + block - 1) / block, U1);
        rowpair_pack_kernel<<<pgrid, block, 0, stream>>>(g1, rp, U1);
        sigmoid_table_kernel<<<(n0_4 + block - 1) / block, block, 0, stream>>>(
            (const float4*)g0, (float4*)s0, n0_4);
        query_rowpair_kernel<<<(N + block - 1) / block, block, 0, stream>>>(
            x, rp, s0, out, N, U1, U0);
    } else if (ws_size >= need_plain && (n1 % 4) == 0 && (n0 % 4) == 0) {
        float* s1 = (float*)d_ws;
        float* s0 = s1 + n1;
        int n1_4 = (int)(n1 / 4), n0_4 = (int)(n0 / 4);
        sigmoid_table_kernel<<<(n1_4 + block - 1) / block, block, 0, stream>>>(
            (const float4*)g1, (float4*)s1, n1_4);
        sigmoid_table_kernel<<<(n0_4 + block - 1) / block, block, 0, stream>>>(
            (const float4*)g0, (float4*)s0, n0_4);
        query_kernel_unpadded<<<(N + block - 1) / block, block, 0, stream>>>(
            x, s1, s0, out, N, U1, U0);
    } else {
        query_kernel_fallback<<<(N + block - 1) / block, block, 0, stream>>>(
            x, g1, g0, out, N, U1, U0);
    }
}